// Round 7
// baseline (253.474 us; speedup 1.0000x reference)
//
#include <hip/hip_runtime.h>
#include <math.h>

#define NUM_TOK 2048
#define HDIM 1024
#define IDIM 2048
#define NEXP 8
#define MAX_ROWS 5120
#define NTM 40

typedef __attribute__((ext_vector_type(8))) short bf16x8;
typedef __attribute__((ext_vector_type(4))) float f32x4;

// ---- workspace offsets (bytes) ----
#define OFF_IDX   0u
#define OFF_RW    16384u
#define OFF_CNT   32768u
#define OFF_SEG   32832u
#define OFF_ROWS  33024u
#define OFF_POS   53504u
#define OFF_XB    131072u
#define OFF_W1T   8388608u
#define OFF_W3T   41943040u
#define OFF_W2T   75497472u
#define OFF_ACT   109051904u
#define OFF_SO    8388608u   /* aliases W1T (dead once gemm2 runs) */

__device__ __forceinline__ unsigned short f2bf(float f) {
  union { float f; unsigned u; } v; v.f = f;
  unsigned r = v.u + 0x7FFF + ((v.u >> 16) & 1);   // RNE
  return (unsigned short)(r >> 16);
}

__device__ __forceinline__ void gld16(const void* g, void* l) {
  __builtin_amdgcn_global_load_lds(
      (const __attribute__((address_space(1))) void*)g,
      (__attribute__((address_space(3))) void*)l, 16, 0, 0);
}

__global__ void k_init(int* __restrict__ cnt, int* __restrict__ rowsv) {
  const int i = blockIdx.x * blockDim.x + threadIdx.x;
  if (i < 16) cnt[i] = 0;
  if (i < MAX_ROWS) rowsv[i] = -1;
}

// fused transpose + fp32->bf16 for all three weights.
// Chained: each block does 4 consecutive 64x64 tiles (64 rows x 256 cols),
// double-buffered LDS + register prefetch of the next tile's loads, ONE
// __syncthreads per tile. Dword-packed +1-padded LDS (conflict-free, R6-proven).
// z 0..7: W1 (H,I)->(I,H); 8..15: W3; 16..23: W2 (I,H)->(H,I)
__global__ void k_wtall(const float* __restrict__ W1, const float* __restrict__ W3,
                        const float* __restrict__ W2,
                        unsigned short* __restrict__ W1T,
                        unsigned short* __restrict__ W3T,
                        unsigned short* __restrict__ W2T) {
  __shared__ unsigned D[2][64 * 33];
  const int z = blockIdx.z;
  const float* src; unsigned short* dst; int R, C, eidx;
  if (z < 8)       { src = W1; dst = W1T; R = HDIM; C = IDIM; eidx = z; }
  else if (z < 16) { src = W3; dst = W3T; R = HDIM; C = IDIM; eidx = z - 8; }
  else             { src = W2; dst = W2T; R = IDIM; C = HDIM; eidx = z - 16; }
  const int r0 = blockIdx.y * 64;
  const int cbase = blockIdx.x * 256;
  if (r0 >= R || cbase >= C) return;
  const int t = threadIdx.x;
  const size_t base = (size_t)eidx * R * C;
  const int c4 = (t & 15) * 4;
  const int r2a = (t >> 4);          // dword-row 0..15 (h adds 16)

  float4 va[2][4];
  auto loadT = [&](int b, int c0) {
#pragma unroll
    for (int h = 0; h < 2; ++h) {
      const int r2 = r2a + h * 16;
      va[b][2 * h]     = *(const float4*)(src + base + (size_t)(r0 + 2 * r2) * C + c0 + c4);
      va[b][2 * h + 1] = *(const float4*)(src + base + (size_t)(r0 + 2 * r2 + 1) * C + c0 + c4);
    }
  };

  loadT(0, cbase);
#pragma unroll
  for (int j = 0; j < 4; ++j) {
    const int c0 = cbase + j * 64;
    const int b = j & 1;
    // transpose-scatter regs -> LDS (bank-safe: stride 33 dwords)
#pragma unroll
    for (int h = 0; h < 2; ++h) {
      const int r2 = r2a + h * 16;
      const float4 v0 = va[b][2 * h], v1 = va[b][2 * h + 1];
      const float a0[4] = {v0.x, v0.y, v0.z, v0.w};
      const float a1[4] = {v1.x, v1.y, v1.z, v1.w};
#pragma unroll
      for (int q = 0; q < 4; ++q)
        D[b][(c4 + q) * 33 + r2] = (unsigned)f2bf(a0[q]) | ((unsigned)f2bf(a1[q]) << 16);
    }
    if (j < 3) loadT(b ^ 1, c0 + 64);   // prefetch next tile under this tile's tail
    __syncthreads();
    const int rq = (t & 7) * 4;
#pragma unroll
    for (int g = 0; g < 2; ++g) {
      const int c = (t >> 3) + g * 32;
      uint4 u;
      u.x = D[b][c * 33 + rq];
      u.y = D[b][c * 33 + rq + 1];
      u.z = D[b][c * 33 + rq + 2];
      u.w = D[b][c * 33 + rq + 3];
      *(uint4*)(dst + base + (size_t)(c0 + c) * R + r0 + rq * 2) = u;
    }
  }
}

__global__ void k_router(const float* __restrict__ x, const float* __restrict__ wg,
                         unsigned short* __restrict__ xb,
                         int* __restrict__ idx, float* __restrict__ rw,
                         int* __restrict__ cnt) {
  const int wave = threadIdx.x >> 6, lane = threadIdx.x & 63;
  const int t = blockIdx.x * 4 + wave;
  const float2* __restrict__ xr = (const float2*)(x + (size_t)t * HDIM);
  unsigned* __restrict__ xbr = (unsigned*)(xb + (size_t)t * HDIM);
  float acc[8];
#pragma unroll
  for (int q = 0; q < 8; ++q) acc[q] = 0.f;
#pragma unroll
  for (int j = 0; j < 8; ++j) {
    const int h2 = lane + (j << 6);
    const float2 v = xr[h2];
    const float* wrow = wg + (size_t)h2 * 16;
    const float4 a0 = *(const float4*)(wrow);
    const float4 a1 = *(const float4*)(wrow + 4);
    const float4 b0 = *(const float4*)(wrow + 8);
    const float4 b1 = *(const float4*)(wrow + 12);
    acc[0] = fmaf(v.x, a0.x, fmaf(v.y, b0.x, acc[0]));
    acc[1] = fmaf(v.x, a0.y, fmaf(v.y, b0.y, acc[1]));
    acc[2] = fmaf(v.x, a0.z, fmaf(v.y, b0.z, acc[2]));
    acc[3] = fmaf(v.x, a0.w, fmaf(v.y, b0.w, acc[3]));
    acc[4] = fmaf(v.x, a1.x, fmaf(v.y, b1.x, acc[4]));
    acc[5] = fmaf(v.x, a1.y, fmaf(v.y, b1.y, acc[5]));
    acc[6] = fmaf(v.x, a1.z, fmaf(v.y, b1.z, acc[6]));
    acc[7] = fmaf(v.x, a1.w, fmaf(v.y, b1.w, acc[7]));
    xbr[h2] = (unsigned)f2bf(v.x) | ((unsigned)f2bf(v.y) << 16);
  }
#pragma unroll
  for (int q = 0; q < 8; ++q) {
#pragma unroll
    for (int off = 32; off >= 1; off >>= 1)
      acc[q] += __shfl_xor(acc[q], off, 64);
  }
  if (lane == 0) {
    int i0 = 0; float v0 = acc[0];
#pragma unroll
    for (int q = 1; q < 8; ++q)
      if (acc[q] > v0) { v0 = acc[q]; i0 = q; }
    int i1 = -1; float v1 = -3.4e38f;
#pragma unroll
    for (int q = 0; q < 8; ++q)
      if (q != i0 && acc[q] > v1) { v1 = acc[q]; i1 = q; }
    const float e1 = expf(v1 - v0);
    const float inv = 1.f / (1.f + e1);
    idx[2 * t] = i0; idx[2 * t + 1] = i1;
    rw[2 * t] = inv; rw[2 * t + 1] = e1 * inv;
    atomicAdd(&cnt[i0], 1);
    atomicAdd(&cnt[i1], 1);
  }
}

// single block: compute 128-aligned expert segments, then scatter slots
__global__ void k_segscatter(const int* __restrict__ cnt, int* __restrict__ seg,
                             int* __restrict__ cursor, const int* __restrict__ idx,
                             int* __restrict__ rowsv, int* __restrict__ pos) {
  __shared__ int sseg[NEXP];
  if (threadIdx.x == 0) {
    int s = 0;
    for (int q = 0; q < NEXP; ++q) {
      seg[q] = s; sseg[q] = s;
      s += ((cnt[q] + 127) / 128) * 128;
    }
    seg[NEXP] = s;
  }
  __syncthreads();
  for (int t = threadIdx.x; t < NUM_TOK; t += 256) {
#pragma unroll
    for (int k = 0; k < 2; ++k) {
      const int slot = 2 * t + k;
      const int e = idx[slot];
      const int p = atomicAdd(&cursor[e], 1);
      const int rr = sseg[e] + p;
      rowsv[rr] = slot;
      pos[slot] = rr;
    }
  }
}

// grouped GEMM1: act = silu(x@W1) * (x@W3); B-tile = 64 W1T rows + 64 W3T rows.
// (R3-proven config: BM=128, BN=64, 4 waves, wave tile 32x64+64, acc[2][8].)
__launch_bounds__(256, 2)
__global__ void k_gemm1(const unsigned short* __restrict__ xb,
                        const unsigned short* __restrict__ W1T,
                        const unsigned short* __restrict__ W3T,
                        const int* __restrict__ seg, const int* __restrict__ rowsv,
                        unsigned short* __restrict__ act) {
  __shared__ __align__(16) unsigned short As[2][128 * 32];
  __shared__ __align__(16) unsigned short Bs[2][128 * 32];
  const int tid = threadIdx.x;
  const int w = tid >> 6, l = tid & 63;
  const int m0 = blockIdx.y * 128;
  const int total = seg[NEXP];
  if (m0 >= total) return;
  int e = 0;
#pragma unroll
  for (int q = 1; q < NEXP; ++q) if (m0 >= seg[q]) e = q;
  const int n0 = blockIdx.x * 64;

  const int swzst = ((l & 3) ^ ((l >> 3) & 3)) * 8;   // staging source column (elems)
  size_t aOff[2], bOff[2];
#pragma unroll
  for (int q = 0; q < 2; ++q) {
    const int r = rowsv[m0 + w * 32 + q * 16 + (l >> 2)];
    const int tk = (r < 0) ? 0 : (r >> 1);
    aOff[q] = (size_t)tk * HDIM + swzst;
    bOff[q] = ((size_t)e * IDIM + n0 + (w & 1) * 32 + q * 16 + (l >> 2)) * HDIM + swzst;
  }
  const unsigned short* __restrict__ WT = (w < 2) ? W1T : W3T;

  f32x4 acc[2][8];
#pragma unroll
  for (int m = 0; m < 2; ++m)
#pragma unroll
    for (int nf = 0; nf < 8; ++nf) acc[m][nf] = (f32x4)0.f;

  auto stage = [&](int buf, int k0) {
#pragma unroll
    for (int q = 0; q < 2; ++q) {
      gld16(xb + aOff[q] + k0, &As[buf][(w * 32 + q * 16) * 32]);
      gld16(WT + bOff[q] + k0, &Bs[buf][(w * 32 + q * 16) * 32]);
    }
  };

  stage(0, 0);
  __syncthreads();
  const int rslot = ((l >> 4) ^ ((l >> 1) & 3)) * 8;  // swizzled read slot (elems)
  const int arow = (w * 32 + (l & 15)) * 32 + rslot;
  for (int t = 0; t < HDIM / 32; ++t) {
    const int cur = t & 1;
    if (t + 1 < HDIM / 32) stage(cur ^ 1, (t + 1) * 32);
    const bf16x8 a0 = *(const bf16x8*)&As[cur][arow];
    const bf16x8 a1 = *(const bf16x8*)&As[cur][arow + 16 * 32];
#pragma unroll
    for (int nf = 0; nf < 8; ++nf) {
      const bf16x8 b = *(const bf16x8*)&Bs[cur][(nf * 16 + (l & 15)) * 32 + rslot];
      acc[0][nf] = __builtin_amdgcn_mfma_f32_16x16x32_bf16(a0, b, acc[0][nf], 0, 0, 0);
      acc[1][nf] = __builtin_amdgcn_mfma_f32_16x16x32_bf16(a1, b, acc[1][nf], 0, 0, 0);
    }
    __syncthreads();
  }
  const int rbase = m0 + w * 32 + (l >> 4) * 4;
  const int cbase = n0 + (l & 15);
#pragma unroll
  for (int m = 0; m < 2; ++m)
#pragma unroll
    for (int p = 0; p < 4; ++p) {
      const f32x4 up = acc[m][p];
      const f32x4 gt = acc[m][p + 4];
#pragma unroll
      for (int r = 0; r < 4; ++r) {
        const float u = up[r];
        const float s = (u / (1.f + expf(-u))) * gt[r];
        act[(size_t)(rbase + m * 16 + r) * IDIM + cbase + p * 16] = f2bf(s);
      }
    }
}

// grouped GEMM2: so[row][h] = act[row] @ W2T[e] (fp32 partials).
// BM=128, BN=128, 4 waves, wave tile 32x128 (acc[2][8]), 16 MFMA : 10 ds_read.
__launch_bounds__(256, 2)
__global__ void k_gemm2(const unsigned short* __restrict__ act,
                        const unsigned short* __restrict__ W2T,
                        const int* __restrict__ seg,
                        float* __restrict__ so) {
  __shared__ __align__(16) unsigned short As[2][128 * 32];
  __shared__ __align__(16) unsigned short Bs[2][128 * 32];
  const int tid = threadIdx.x;
  const int w = tid >> 6, l = tid & 63;
  const int m0 = blockIdx.y * 128;
  const int total = seg[NEXP];
  if (m0 >= total) return;
  int e = 0;
#pragma unroll
  for (int q = 1; q < NEXP; ++q) if (m0 >= seg[q]) e = q;
  const int n0 = blockIdx.x * 128;
  const int swz = ((tid & 3) ^ ((tid >> 3) & 3)) * 8;  // staging source col (elems)
  size_t aOff[2], bOff[2];
#pragma unroll
  for (int q = 0; q < 2; ++q) {
    aOff[q] = (size_t)(m0 + q * 64 + (tid >> 2)) * IDIM + swz;
    bOff[q] = ((size_t)e * HDIM + n0 + q * 64 + (tid >> 2)) * IDIM + swz;
  }

  f32x4 acc[2][8];
#pragma unroll
  for (int mf = 0; mf < 2; ++mf)
#pragma unroll
    for (int nf = 0; nf < 8; ++nf) acc[mf][nf] = (f32x4)0.f;

  auto stage = [&](int buf, int k0) {
#pragma unroll
    for (int q = 0; q < 2; ++q) {
      gld16(act + aOff[q] + k0, &As[buf][(q * 64 + (tid >> 2)) * 32 + (tid & 3) * 8]);
      gld16(W2T + bOff[q] + k0, &Bs[buf][(q * 64 + (tid >> 2)) * 32 + (tid & 3) * 8]);
    }
  };

  stage(0, 0);
  __syncthreads();
  const int rslot = ((l >> 4) ^ ((l >> 1) & 3)) * 8;   // swizzled read slot (elems)
  const int arow = (w * 32 + (l & 15)) * 32 + rslot;
  for (int t = 0; t < IDIM / 32; ++t) {
    const int cur = t & 1;
    if (t + 1 < IDIM / 32) stage(cur ^ 1, (t + 1) * 32);
    const bf16x8 a0 = *(const bf16x8*)&As[cur][arow];
    const bf16x8 a1 = *(const bf16x8*)&As[cur][arow + 16 * 32];
#pragma unroll
    for (int nf = 0; nf < 8; ++nf) {
      const bf16x8 b = *(const bf16x8*)&Bs[cur][(nf * 16 + (l & 15)) * 32 + rslot];
      acc[0][nf] = __builtin_amdgcn_mfma_f32_16x16x32_bf16(a0, b, acc[0][nf], 0, 0, 0);
      acc[1][nf] = __builtin_amdgcn_mfma_f32_16x16x32_bf16(a1, b, acc[1][nf], 0, 0, 0);
    }
    __syncthreads();
  }
  const int rbase = m0 + w * 32 + (l >> 4) * 4;
  const int cbase = n0 + (l & 15);
#pragma unroll
  for (int mf = 0; mf < 2; ++mf)
#pragma unroll
    for (int nf = 0; nf < 8; ++nf)
#pragma unroll
      for (int r = 0; r < 4; ++r)
        so[(size_t)(rbase + mf * 16 + r) * HDIM + cbase + nf * 16] = acc[mf][nf][r];
}

__global__ void k_combine(const float* __restrict__ so, const int* __restrict__ pos,
                          const float* __restrict__ rw, float* __restrict__ out) {
  const int t = blockIdx.x, i = threadIdx.x;
  const int p0 = pos[2 * t], p1 = pos[2 * t + 1];
  const float w0 = rw[2 * t], w1 = rw[2 * t + 1];
  const float4 a = ((const float4*)(so + (size_t)p0 * HDIM))[i];
  const float4 b = ((const float4*)(so + (size_t)p1 * HDIM))[i];
  float4 o;
  o.x = w0 * a.x + w1 * b.x;
  o.y = w0 * a.y + w1 * b.y;
  o.z = w0 * a.z + w1 * b.z;
  o.w = w0 * a.w + w1 * b.w;
  ((float4*)(out + (size_t)t * HDIM))[i] = o;
}

extern "C" void kernel_launch(void* const* d_in, const int* in_sizes, int n_in,
                              void* d_out, int out_size, void* d_ws, size_t ws_size,
                              hipStream_t stream) {
  const float* x  = (const float*)d_in[0];
  const float* Wg = (const float*)d_in[1];
  const float* W1 = (const float*)d_in[2];
  const float* W2 = (const float*)d_in[3];   // (E, I, H)
  const float* W3 = (const float*)d_in[4];   // (E, H, I)
  float* out = (float*)d_out;
  char* ws = (char*)d_ws;
  int*   idx  = (int*)(ws + OFF_IDX);
  float* rw   = (float*)(ws + OFF_RW);
  int*   cnt  = (int*)(ws + OFF_CNT);
  int*   seg  = (int*)(ws + OFF_SEG);
  int*   rowsv= (int*)(ws + OFF_ROWS);
  int*   pos  = (int*)(ws + OFF_POS);
  unsigned short* xb  = (unsigned short*)(ws + OFF_XB);
  unsigned short* W1T = (unsigned short*)(ws + OFF_W1T);
  unsigned short* W3T = (unsigned short*)(ws + OFF_W3T);
  unsigned short* W2T = (unsigned short*)(ws + OFF_W2T);
  unsigned short* act = (unsigned short*)(ws + OFF_ACT);
  float* so = (float*)(ws + OFF_SO);

  k_init<<<20, 256, 0, stream>>>(cnt, rowsv);
  k_wtall<<<dim3(8, 32, 24), 256, 0, stream>>>(W1, W3, W2, W1T, W3T, W2T);
  k_router<<<NUM_TOK / 4, 256, 0, stream>>>(x, Wg, xb, idx, rw, cnt);
  k_segscatter<<<1, 256, 0, stream>>>(cnt, seg, cnt + 8, idx, rowsv, pos);
  k_gemm1<<<dim3(IDIM / 64, NTM), 256, 0, stream>>>(xb, W1T, W3T, seg, rowsv, act);
  k_gemm2<<<dim3(HDIM / 128, NTM), 256, 0, stream>>>(act, W2T, seg, so);
  k_combine<<<NUM_TOK, 256, 0, stream>>>(so, pos, rw, out);
}

// Round 9
// 187.769 us; speedup vs baseline: 1.3499x; 1.3499x over previous
//
#include <hip/hip_runtime.h>
#include <math.h>

#define NUM_TOK 2048
#define HDIM 1024
#define IDIM 2048
#define NEXP 8
#define MAX_ROWS 5120
#define NTM 40

typedef __attribute__((ext_vector_type(8))) short bf16x8;
typedef __attribute__((ext_vector_type(4))) float f32x4;

// ---- workspace offsets (bytes) ----
#define OFF_IDX   0u
#define OFF_RW    16384u
#define OFF_CNT   32768u
#define OFF_SEG   32832u
#define OFF_ROWS  33024u
#define OFF_POS   53504u
#define OFF_XB    131072u
#define OFF_W1T   8388608u
#define OFF_W3T   41943040u
#define OFF_W2T   75497472u
#define OFF_ACT   109051904u
#define OFF_SO    8388608u   /* aliases W1T (dead once gemm2 runs) */

__device__ __forceinline__ unsigned short f2bf(float f) {
  union { float f; unsigned u; } v; v.f = f;
  unsigned r = v.u + 0x7FFF + ((v.u >> 16) & 1);   // RNE
  return (unsigned short)(r >> 16);
}

__device__ __forceinline__ void gld16(const void* g, void* l) {
  __builtin_amdgcn_global_load_lds(
      (const __attribute__((address_space(1))) void*)g,
      (__attribute__((address_space(3))) void*)l, 16, 0, 0);
}

// Fused prep: weight transpose+cvt (z<24) and router (z 24..25).
// Transpose tile: 256 rows x 64 cols per block. All 16 float4 loads issued
// up-front (64KB in flight/block), ONE barrier, stores in 512B contiguous
// column segments (32 lanes x 16B). LDS stride 129 dwords (==1 mod 32).
__global__ void k_prep(const float* __restrict__ W1, const float* __restrict__ W3,
                       const float* __restrict__ W2,
                       unsigned short* __restrict__ W1T,
                       unsigned short* __restrict__ W3T,
                       unsigned short* __restrict__ W2T,
                       const float* __restrict__ x, const float* __restrict__ wg,
                       unsigned short* __restrict__ xb,
                       int* __restrict__ idx, float* __restrict__ rw) {
  __shared__ unsigned D[64 * 129];
  const int z = blockIdx.z;
  const int t = threadIdx.x;
  if (z >= 24) {
    // ---------------- router ----------------
    const int wave = t >> 6, lane = t & 63;
    const int id = blockIdx.x + 32 * blockIdx.y + 256 * (z - 24);
    const int tok = id * 4 + wave;
    if (tok >= NUM_TOK) return;
    const float2* __restrict__ xr = (const float2*)(x + (size_t)tok * HDIM);
    unsigned* __restrict__ xbr = (unsigned*)(xb + (size_t)tok * HDIM);
    float acc[8];
#pragma unroll
    for (int q = 0; q < 8; ++q) acc[q] = 0.f;
#pragma unroll
    for (int j = 0; j < 8; ++j) {
      const int h2 = lane + (j << 6);
      const float2 v = xr[h2];
      const float* wrow = wg + (size_t)h2 * 16;
      const float4 a0 = *(const float4*)(wrow);
      const float4 a1 = *(const float4*)(wrow + 4);
      const float4 b0 = *(const float4*)(wrow + 8);
      const float4 b1 = *(const float4*)(wrow + 12);
      acc[0] = fmaf(v.x, a0.x, fmaf(v.y, b0.x, acc[0]));
      acc[1] = fmaf(v.x, a0.y, fmaf(v.y, b0.y, acc[1]));
      acc[2] = fmaf(v.x, a0.z, fmaf(v.y, b0.z, acc[2]));
      acc[3] = fmaf(v.x, a0.w, fmaf(v.y, b0.w, acc[3]));
      acc[4] = fmaf(v.x, a1.x, fmaf(v.y, b1.x, acc[4]));
      acc[5] = fmaf(v.x, a1.y, fmaf(v.y, b1.y, acc[5]));
      acc[6] = fmaf(v.x, a1.z, fmaf(v.y, b1.z, acc[6]));
      acc[7] = fmaf(v.x, a1.w, fmaf(v.y, b1.w, acc[7]));
      xbr[h2] = (unsigned)f2bf(v.x) | ((unsigned)f2bf(v.y) << 16);
    }
#pragma unroll
    for (int q = 0; q < 8; ++q) {
#pragma unroll
      for (int off = 32; off >= 1; off >>= 1)
        acc[q] += __shfl_xor(acc[q], off, 64);
    }
    if (lane == 0) {
      int i0 = 0; float v0 = acc[0];
#pragma unroll
      for (int q = 1; q < 8; ++q)
        if (acc[q] > v0) { v0 = acc[q]; i0 = q; }
      int i1 = -1; float v1 = -3.4e38f;
#pragma unroll
      for (int q = 0; q < 8; ++q)
        if (q != i0 && acc[q] > v1) { v1 = acc[q]; i1 = q; }
      const float e1 = expf(v1 - v0);
      const float inv = 1.f / (1.f + e1);
      idx[2 * tok] = i0; idx[2 * tok + 1] = i1;
      rw[2 * tok] = inv; rw[2 * tok + 1] = e1 * inv;
    }
    return;
  }
  // ---------------- weight transpose ----------------
  const float* src; unsigned short* dst; int R, C, eidx;
  if (z < 8)       { src = W1; dst = W1T; R = HDIM; C = IDIM; eidx = z; }
  else if (z < 16) { src = W3; dst = W3T; R = HDIM; C = IDIM; eidx = z - 8; }
  else             { src = W2; dst = W2T; R = IDIM; C = HDIM; eidx = z - 16; }
  const int r0 = blockIdx.y * 256;
  const int c0 = blockIdx.x * 64;
  if (r0 >= R || c0 >= C) return;
  const size_t base = (size_t)eidx * R * C;
  const int c4 = (t & 15) * 4;
  const int r2a = t >> 4;                    // 0..15
  // issue all 16 loads first (max MLP)
  float4 va[4][2][2];
#pragma unroll
  for (int p = 0; p < 4; ++p)
#pragma unroll
    for (int h = 0; h < 2; ++h) {
      const int r = r0 + p * 64 + 2 * (r2a + 16 * h);
      va[p][h][0] = *(const float4*)(src + base + (size_t)r * C + c0 + c4);
      va[p][h][1] = *(const float4*)(src + base + (size_t)(r + 1) * C + c0 + c4);
    }
  // convert + transpose-scatter into LDS (dword-packed, stride 129)
#pragma unroll
  for (int p = 0; p < 4; ++p)
#pragma unroll
    for (int h = 0; h < 2; ++h) {
      const int r2 = p * 32 + r2a + 16 * h;  // dword-row 0..127
      const float4 v0 = va[p][h][0], v1 = va[p][h][1];
      const float a0[4] = {v0.x, v0.y, v0.z, v0.w};
      const float a1[4] = {v1.x, v1.y, v1.z, v1.w};
#pragma unroll
      for (int q = 0; q < 4; ++q)
        D[(c4 + q) * 129 + r2] = (unsigned)f2bf(a0[q]) | ((unsigned)f2bf(a1[q]) << 16);
    }
  __syncthreads();
  // store: 512B contiguous per 32 lanes, column-major output
  const int rq = (t & 31) * 4;               // dword offset in column
#pragma unroll
  for (int g = 0; g < 8; ++g) {
    const int c = (t >> 5) + g * 8;          // FIX: bijective over 0..63
    uint4 u;
    u.x = D[c * 129 + rq];
    u.y = D[c * 129 + rq + 1];
    u.z = D[c * 129 + rq + 2];
    u.w = D[c * 129 + rq + 3];
    *(uint4*)(dst + base + (size_t)(c0 + c) * R + r0 + rq * 2) = u;
  }
}

// single block: histogram -> 128-aligned segments -> scatter (replaces k_init too)
__global__ void k_segscatter(const int* __restrict__ idx, int* __restrict__ seg,
                             int* __restrict__ rowsv, int* __restrict__ pos) {
  __shared__ int hist[NEXP], cur[NEXP], sseg[NEXP];
  const int tid = threadIdx.x;
  if (tid < NEXP) { hist[tid] = 0; cur[tid] = 0; }
  __syncthreads();
  for (int s = tid; s < 2 * NUM_TOK; s += 256) atomicAdd(&hist[idx[s]], 1);
  for (int r = tid; r < MAX_ROWS; r += 256) rowsv[r] = -1;
  __syncthreads();
  if (tid == 0) {
    int s = 0;
    for (int q = 0; q < NEXP; ++q) {
      seg[q] = s; sseg[q] = s;
      s += ((hist[q] + 127) / 128) * 128;
    }
    seg[NEXP] = s;
  }
  __syncthreads();
  for (int s = tid; s < 2 * NUM_TOK; s += 256) {
    const int e = idx[s];
    const int p = atomicAdd(&cur[e], 1);
    const int rr = sseg[e] + p;
    rowsv[rr] = s;
    pos[s] = rr;
  }
}

// grouped GEMM1: act = silu(x@W1) * (x@W3); B-tile = 64 W1T rows + 64 W3T rows.
// (R3-proven config: BM=128, BN=64, 4 waves, wave tile 32x64+64, acc[2][8].)
__launch_bounds__(256, 2)
__global__ void k_gemm1(const unsigned short* __restrict__ xb,
                        const unsigned short* __restrict__ W1T,
                        const unsigned short* __restrict__ W3T,
                        const int* __restrict__ seg, const int* __restrict__ rowsv,
                        unsigned short* __restrict__ act) {
  __shared__ __align__(16) unsigned short As[2][128 * 32];
  __shared__ __align__(16) unsigned short Bs[2][128 * 32];
  const int tid = threadIdx.x;
  const int w = tid >> 6, l = tid & 63;
  const int m0 = blockIdx.y * 128;
  const int total = seg[NEXP];
  if (m0 >= total) return;
  int e = 0;
#pragma unroll
  for (int q = 1; q < NEXP; ++q) if (m0 >= seg[q]) e = q;
  const int n0 = blockIdx.x * 64;

  const int swzst = ((l & 3) ^ ((l >> 3) & 3)) * 8;   // staging source column (elems)
  size_t aOff[2], bOff[2];
#pragma unroll
  for (int q = 0; q < 2; ++q) {
    const int r = rowsv[m0 + w * 32 + q * 16 + (l >> 2)];
    const int tk = (r < 0) ? 0 : (r >> 1);
    aOff[q] = (size_t)tk * HDIM + swzst;
    bOff[q] = ((size_t)e * IDIM + n0 + (w & 1) * 32 + q * 16 + (l >> 2)) * HDIM + swzst;
  }
  const unsigned short* __restrict__ WT = (w < 2) ? W1T : W3T;

  f32x4 acc[2][8];
#pragma unroll
  for (int m = 0; m < 2; ++m)
#pragma unroll
    for (int nf = 0; nf < 8; ++nf) acc[m][nf] = (f32x4)0.f;

  auto stage = [&](int buf, int k0) {
#pragma unroll
    for (int q = 0; q < 2; ++q) {
      gld16(xb + aOff[q] + k0, &As[buf][(w * 32 + q * 16) * 32]);
      gld16(WT + bOff[q] + k0, &Bs[buf][(w * 32 + q * 16) * 32]);
    }
  };

  stage(0, 0);
  __syncthreads();
  const int rslot = ((l >> 4) ^ ((l >> 1) & 3)) * 8;  // swizzled read slot (elems)
  const int arow = (w * 32 + (l & 15)) * 32 + rslot;
  for (int t = 0; t < HDIM / 32; ++t) {
    const int cur = t & 1;
    if (t + 1 < HDIM / 32) stage(cur ^ 1, (t + 1) * 32);
    const bf16x8 a0 = *(const bf16x8*)&As[cur][arow];
    const bf16x8 a1 = *(const bf16x8*)&As[cur][arow + 16 * 32];
#pragma unroll
    for (int nf = 0; nf < 8; ++nf) {
      const bf16x8 b = *(const bf16x8*)&Bs[cur][(nf * 16 + (l & 15)) * 32 + rslot];
      acc[0][nf] = __builtin_amdgcn_mfma_f32_16x16x32_bf16(a0, b, acc[0][nf], 0, 0, 0);
      acc[1][nf] = __builtin_amdgcn_mfma_f32_16x16x32_bf16(a1, b, acc[1][nf], 0, 0, 0);
    }
    __syncthreads();
  }
  const int rbase = m0 + w * 32 + (l >> 4) * 4;
  const int cbase = n0 + (l & 15);
#pragma unroll
  for (int m = 0; m < 2; ++m)
#pragma unroll
    for (int p = 0; p < 4; ++p) {
      const f32x4 up = acc[m][p];
      const f32x4 gt = acc[m][p + 4];
#pragma unroll
      for (int r = 0; r < 4; ++r) {
        const float u = up[r];
        const float s = (u / (1.f + expf(-u))) * gt[r];
        act[(size_t)(rbase + m * 16 + r) * IDIM + cbase + p * 16] = f2bf(s);
      }
    }
}

// grouped GEMM2: so[row][h] = act[row] @ W2T[e] (fp32 partials).
// BM=128, BN=128, 4 waves, wave tile 32x128 (acc[2][8]), 16 MFMA : 10 ds_read.
__launch_bounds__(256, 2)
__global__ void k_gemm2(const unsigned short* __restrict__ act,
                        const unsigned short* __restrict__ W2T,
                        const int* __restrict__ seg,
                        float* __restrict__ so) {
  __shared__ __align__(16) unsigned short As[2][128 * 32];
  __shared__ __align__(16) unsigned short Bs[2][128 * 32];
  const int tid = threadIdx.x;
  const int w = tid >> 6, l = tid & 63;
  const int m0 = blockIdx.y * 128;
  const int total = seg[NEXP];
  if (m0 >= total) return;
  int e = 0;
#pragma unroll
  for (int q = 1; q < NEXP; ++q) if (m0 >= seg[q]) e = q;
  const int n0 = blockIdx.x * 128;
  const int swz = ((tid & 3) ^ ((tid >> 3) & 3)) * 8;  // staging source col (elems)
  size_t aOff[2], bOff[2];
#pragma unroll
  for (int q = 0; q < 2; ++q) {
    aOff[q] = (size_t)(m0 + q * 64 + (tid >> 2)) * IDIM + swz;
    bOff[q] = ((size_t)e * HDIM + n0 + q * 64 + (tid >> 2)) * IDIM + swz;
  }

  f32x4 acc[2][8];
#pragma unroll
  for (int mf = 0; mf < 2; ++mf)
#pragma unroll
    for (int nf = 0; nf < 8; ++nf) acc[mf][nf] = (f32x4)0.f;

  auto stage = [&](int buf, int k0) {
#pragma unroll
    for (int q = 0; q < 2; ++q) {
      gld16(act + aOff[q] + k0, &As[buf][(q * 64 + (tid >> 2)) * 32 + (tid & 3) * 8]);
      gld16(W2T + bOff[q] + k0, &Bs[buf][(q * 64 + (tid >> 2)) * 32 + (tid & 3) * 8]);
    }
  };

  stage(0, 0);
  __syncthreads();
  const int rslot = ((l >> 4) ^ ((l >> 1) & 3)) * 8;   // swizzled read slot (elems)
  const int arow = (w * 32 + (l & 15)) * 32 + rslot;
  for (int t = 0; t < IDIM / 32; ++t) {
    const int cur = t & 1;
    if (t + 1 < IDIM / 32) stage(cur ^ 1, (t + 1) * 32);
    const bf16x8 a0 = *(const bf16x8*)&As[cur][arow];
    const bf16x8 a1 = *(const bf16x8*)&As[cur][arow + 16 * 32];
#pragma unroll
    for (int nf = 0; nf < 8; ++nf) {
      const bf16x8 b = *(const bf16x8*)&Bs[cur][(nf * 16 + (l & 15)) * 32 + rslot];
      acc[0][nf] = __builtin_amdgcn_mfma_f32_16x16x32_bf16(a0, b, acc[0][nf], 0, 0, 0);
      acc[1][nf] = __builtin_amdgcn_mfma_f32_16x16x32_bf16(a1, b, acc[1][nf], 0, 0, 0);
    }
    __syncthreads();
  }
  const int rbase = m0 + w * 32 + (l >> 4) * 4;
  const int cbase = n0 + (l & 15);
#pragma unroll
  for (int mf = 0; mf < 2; ++mf)
#pragma unroll
    for (int nf = 0; nf < 8; ++nf)
#pragma unroll
      for (int r = 0; r < 4; ++r)
        so[(size_t)(rbase + mf * 16 + r) * HDIM + cbase + nf * 16] = acc[mf][nf][r];
}

__global__ void k_combine(const float* __restrict__ so, const int* __restrict__ pos,
                          const float* __restrict__ rw, float* __restrict__ out) {
  const int t = blockIdx.x, i = threadIdx.x;
  const int p0 = pos[2 * t], p1 = pos[2 * t + 1];
  const float w0 = rw[2 * t], w1 = rw[2 * t + 1];
  const float4 a = ((const float4*)(so + (size_t)p0 * HDIM))[i];
  const float4 b = ((const float4*)(so + (size_t)p1 * HDIM))[i];
  float4 o;
  o.x = w0 * a.x + w1 * b.x;
  o.y = w0 * a.y + w1 * b.y;
  o.z = w0 * a.z + w1 * b.z;
  o.w = w0 * a.w + w1 * b.w;
  ((float4*)(out + (size_t)t * HDIM))[i] = o;
}

extern "C" void kernel_launch(void* const* d_in, const int* in_sizes, int n_in,
                              void* d_out, int out_size, void* d_ws, size_t ws_size,
                              hipStream_t stream) {
  const float* x  = (const float*)d_in[0];
  const float* Wg = (const float*)d_in[1];
  const float* W1 = (const float*)d_in[2];
  const float* W2 = (const float*)d_in[3];   // (E, I, H)
  const float* W3 = (const float*)d_in[4];   // (E, H, I)
  float* out = (float*)d_out;
  char* ws = (char*)d_ws;
  int*   idx  = (int*)(ws + OFF_IDX);
  float* rw   = (float*)(ws + OFF_RW);
  int*   seg  = (int*)(ws + OFF_SEG);
  int*   rowsv= (int*)(ws + OFF_ROWS);
  int*   pos  = (int*)(ws + OFF_POS);
  unsigned short* xb  = (unsigned short*)(ws + OFF_XB);
  unsigned short* W1T = (unsigned short*)(ws + OFF_W1T);
  unsigned short* W3T = (unsigned short*)(ws + OFF_W3T);
  unsigned short* W2T = (unsigned short*)(ws + OFF_W2T);
  unsigned short* act = (unsigned short*)(ws + OFF_ACT);
  float* so = (float*)(ws + OFF_SO);

  k_prep<<<dim3(32, 8, 26), 256, 0, stream>>>(W1, W3, W2, W1T, W3T, W2T,
                                              x, Wg, xb, idx, rw);
  k_segscatter<<<1, 256, 0, stream>>>(idx, seg, rowsv, pos);
  k_gemm1<<<dim3(IDIM / 64, NTM), 256, 0, stream>>>(xb, W1T, W3T, seg, rowsv, act);
  k_gemm2<<<dim3(HDIM / 128, NTM), 256, 0, stream>>>(act, W2T, seg, so);
  k_combine<<<NUM_TOK, 256, 0, stream>>>(so, pos, rw, out);
}

// Round 10
// 186.827 us; speedup vs baseline: 1.3567x; 1.0050x over previous
//
#include <hip/hip_runtime.h>
#include <math.h>

#define NUM_TOK 2048
#define HDIM 1024
#define IDIM 2048
#define NEXP 8
#define MAX_ROWS 5120
#define NTM 40

typedef __attribute__((ext_vector_type(8))) short bf16x8;
typedef __attribute__((ext_vector_type(4))) float f32x4;

// ---- workspace offsets (bytes) ----
#define OFF_IDX   0u
#define OFF_RW    16384u
#define OFF_CNT   32768u
#define OFF_SEG   32832u
#define OFF_ROWS  33024u
#define OFF_POS   53504u
#define OFF_XB    131072u
#define OFF_W1T   8388608u
#define OFF_W3T   41943040u
#define OFF_W2T   75497472u
#define OFF_ACT   109051904u
#define OFF_SO    8388608u   /* aliases W1T (dead once gemm2 runs) */

__device__ __forceinline__ unsigned short f2bf(float f) {
  union { float f; unsigned u; } v; v.f = f;
  unsigned r = v.u + 0x7FFF + ((v.u >> 16) & 1);   // RNE
  return (unsigned short)(r >> 16);
}

__device__ __forceinline__ void gld16(const void* g, void* l) {
  __builtin_amdgcn_global_load_lds(
      (const __attribute__((address_space(1))) void*)g,
      (__attribute__((address_space(3))) void*)l, 16, 0, 0);
}

// Fused prep: weight transpose+cvt (z<24) and router (z 24..25).
// Transpose tile: 256 rows x 64 cols per block. All 16 float4 loads issued
// up-front (64KB in flight/block) — sched_barrier(0) pins the issue order so
// the allocator cannot sink loads to their uses (R9: VGPR=40 proved it did).
// ONE barrier, stores in 512B contiguous column segments. LDS stride 129.
__global__ void __launch_bounds__(256, 4)
k_prep(const float* __restrict__ W1, const float* __restrict__ W3,
       const float* __restrict__ W2,
       unsigned short* __restrict__ W1T,
       unsigned short* __restrict__ W3T,
       unsigned short* __restrict__ W2T,
       const float* __restrict__ x, const float* __restrict__ wg,
       unsigned short* __restrict__ xb,
       int* __restrict__ idx, float* __restrict__ rw) {
  __shared__ unsigned D[64 * 129];
  const int z = blockIdx.z;
  const int t = threadIdx.x;
  if (z >= 24) {
    // ---------------- router ----------------
    const int wave = t >> 6, lane = t & 63;
    const int id = blockIdx.x + 32 * blockIdx.y + 256 * (z - 24);
    const int tok = id * 4 + wave;
    if (tok >= NUM_TOK) return;
    const float2* __restrict__ xr = (const float2*)(x + (size_t)tok * HDIM);
    unsigned* __restrict__ xbr = (unsigned*)(xb + (size_t)tok * HDIM);
    float acc[8];
#pragma unroll
    for (int q = 0; q < 8; ++q) acc[q] = 0.f;
#pragma unroll
    for (int j = 0; j < 8; ++j) {
      const int h2 = lane + (j << 6);
      const float2 v = xr[h2];
      const float* wrow = wg + (size_t)h2 * 16;
      const float4 a0 = *(const float4*)(wrow);
      const float4 a1 = *(const float4*)(wrow + 4);
      const float4 b0 = *(const float4*)(wrow + 8);
      const float4 b1 = *(const float4*)(wrow + 12);
      acc[0] = fmaf(v.x, a0.x, fmaf(v.y, b0.x, acc[0]));
      acc[1] = fmaf(v.x, a0.y, fmaf(v.y, b0.y, acc[1]));
      acc[2] = fmaf(v.x, a0.z, fmaf(v.y, b0.z, acc[2]));
      acc[3] = fmaf(v.x, a0.w, fmaf(v.y, b0.w, acc[3]));
      acc[4] = fmaf(v.x, a1.x, fmaf(v.y, b1.x, acc[4]));
      acc[5] = fmaf(v.x, a1.y, fmaf(v.y, b1.y, acc[5]));
      acc[6] = fmaf(v.x, a1.z, fmaf(v.y, b1.z, acc[6]));
      acc[7] = fmaf(v.x, a1.w, fmaf(v.y, b1.w, acc[7]));
      xbr[h2] = (unsigned)f2bf(v.x) | ((unsigned)f2bf(v.y) << 16);
    }
#pragma unroll
    for (int q = 0; q < 8; ++q) {
#pragma unroll
      for (int off = 32; off >= 1; off >>= 1)
        acc[q] += __shfl_xor(acc[q], off, 64);
    }
    if (lane == 0) {
      int i0 = 0; float v0 = acc[0];
#pragma unroll
      for (int q = 1; q < 8; ++q)
        if (acc[q] > v0) { v0 = acc[q]; i0 = q; }
      int i1 = -1; float v1 = -3.4e38f;
#pragma unroll
      for (int q = 0; q < 8; ++q)
        if (q != i0 && acc[q] > v1) { v1 = acc[q]; i1 = q; }
      const float e1 = expf(v1 - v0);
      const float inv = 1.f / (1.f + e1);
      idx[2 * tok] = i0; idx[2 * tok + 1] = i1;
      rw[2 * tok] = inv; rw[2 * tok + 1] = e1 * inv;
    }
    return;
  }
  // ---------------- weight transpose ----------------
  const float* src; unsigned short* dst; int R, C, eidx;
  if (z < 8)       { src = W1; dst = W1T; R = HDIM; C = IDIM; eidx = z; }
  else if (z < 16) { src = W3; dst = W3T; R = HDIM; C = IDIM; eidx = z - 8; }
  else             { src = W2; dst = W2T; R = IDIM; C = HDIM; eidx = z - 16; }
  const int r0 = blockIdx.y * 256;
  const int c0 = blockIdx.x * 64;
  if (r0 >= R || c0 >= C) return;
  const size_t base = (size_t)eidx * R * C;
  const int c4 = (t & 15) * 4;
  const int r2a = t >> 4;                    // 0..15
  // issue all 16 loads first (max MLP)
  float4 va[4][2][2];
#pragma unroll
  for (int p = 0; p < 4; ++p)
#pragma unroll
    for (int h = 0; h < 2; ++h) {
      const int r = r0 + p * 64 + 2 * (r2a + 16 * h);
      va[p][h][0] = *(const float4*)(src + base + (size_t)r * C + c0 + c4);
      va[p][h][1] = *(const float4*)(src + base + (size_t)(r + 1) * C + c0 + c4);
    }
  __builtin_amdgcn_sched_barrier(0);   // pin: all loads issued before any use
  // convert + transpose-scatter into LDS (dword-packed, stride 129)
#pragma unroll
  for (int p = 0; p < 4; ++p)
#pragma unroll
    for (int h = 0; h < 2; ++h) {
      const int r2 = p * 32 + r2a + 16 * h;  // dword-row 0..127
      const float4 v0 = va[p][h][0], v1 = va[p][h][1];
      const float a0[4] = {v0.x, v0.y, v0.z, v0.w};
      const float a1[4] = {v1.x, v1.y, v1.z, v1.w};
#pragma unroll
      for (int q = 0; q < 4; ++q)
        D[(c4 + q) * 129 + r2] = (unsigned)f2bf(a0[q]) | ((unsigned)f2bf(a1[q]) << 16);
    }
  __syncthreads();
  // store: 512B contiguous per 32 lanes, column-major output
  const int rq = (t & 31) * 4;               // dword offset in column
#pragma unroll
  for (int g = 0; g < 8; ++g) {
    const int c = (t >> 5) + g * 8;          // bijective over 0..63
    uint4 u;
    u.x = D[c * 129 + rq];
    u.y = D[c * 129 + rq + 1];
    u.z = D[c * 129 + rq + 2];
    u.w = D[c * 129 + rq + 3];
    *(uint4*)(dst + base + (size_t)(c0 + c) * R + r0 + rq * 2) = u;
  }
}

// single block: histogram -> 128-aligned segments -> scatter
__global__ void k_segscatter(const int* __restrict__ idx, int* __restrict__ seg,
                             int* __restrict__ rowsv, int* __restrict__ pos) {
  __shared__ int hist[NEXP], cur[NEXP], sseg[NEXP];
  const int tid = threadIdx.x;
  if (tid < NEXP) { hist[tid] = 0; cur[tid] = 0; }
  __syncthreads();
  for (int s = tid; s < 2 * NUM_TOK; s += 256) atomicAdd(&hist[idx[s]], 1);
  for (int r = tid; r < MAX_ROWS; r += 256) rowsv[r] = -1;
  __syncthreads();
  if (tid == 0) {
    int s = 0;
    for (int q = 0; q < NEXP; ++q) {
      seg[q] = s; sseg[q] = s;
      s += ((hist[q] + 127) / 128) * 128;
    }
    seg[NEXP] = s;
  }
  __syncthreads();
  for (int s = tid; s < 2 * NUM_TOK; s += 256) {
    const int e = idx[s];
    const int p = atomicAdd(&cur[e], 1);
    const int rr = sseg[e] + p;
    rowsv[rr] = s;
    pos[s] = rr;
  }
}

// grouped GEMM1: act = silu(x@W1) * (x@W3); B-tile = 64 W1T rows + 64 W3T rows.
// (R3-proven config: BM=128, BN=64, 4 waves, wave tile 32x64+64, acc[2][8].)
__launch_bounds__(256, 2)
__global__ void k_gemm1(const unsigned short* __restrict__ xb,
                        const unsigned short* __restrict__ W1T,
                        const unsigned short* __restrict__ W3T,
                        const int* __restrict__ seg, const int* __restrict__ rowsv,
                        unsigned short* __restrict__ act) {
  __shared__ __align__(16) unsigned short As[2][128 * 32];
  __shared__ __align__(16) unsigned short Bs[2][128 * 32];
  const int tid = threadIdx.x;
  const int w = tid >> 6, l = tid & 63;
  const int m0 = blockIdx.y * 128;
  const int total = seg[NEXP];
  if (m0 >= total) return;
  int e = 0;
#pragma unroll
  for (int q = 1; q < NEXP; ++q) if (m0 >= seg[q]) e = q;
  const int n0 = blockIdx.x * 64;

  const int swzst = ((l & 3) ^ ((l >> 3) & 3)) * 8;   // staging source column (elems)
  size_t aOff[2], bOff[2];
#pragma unroll
  for (int q = 0; q < 2; ++q) {
    const int r = rowsv[m0 + w * 32 + q * 16 + (l >> 2)];
    const int tk = (r < 0) ? 0 : (r >> 1);
    aOff[q] = (size_t)tk * HDIM + swzst;
    bOff[q] = ((size_t)e * IDIM + n0 + (w & 1) * 32 + q * 16 + (l >> 2)) * HDIM + swzst;
  }
  const unsigned short* __restrict__ WT = (w < 2) ? W1T : W3T;

  f32x4 acc[2][8];
#pragma unroll
  for (int m = 0; m < 2; ++m)
#pragma unroll
    for (int nf = 0; nf < 8; ++nf) acc[m][nf] = (f32x4)0.f;

  auto stage = [&](int buf, int k0) {
#pragma unroll
    for (int q = 0; q < 2; ++q) {
      gld16(xb + aOff[q] + k0, &As[buf][(w * 32 + q * 16) * 32]);
      gld16(WT + bOff[q] + k0, &Bs[buf][(w * 32 + q * 16) * 32]);
    }
  };

  stage(0, 0);
  __syncthreads();
  const int rslot = ((l >> 4) ^ ((l >> 1) & 3)) * 8;  // swizzled read slot (elems)
  const int arow = (w * 32 + (l & 15)) * 32 + rslot;
  for (int t = 0; t < HDIM / 32; ++t) {
    const int cur = t & 1;
    if (t + 1 < HDIM / 32) stage(cur ^ 1, (t + 1) * 32);
    const bf16x8 a0 = *(const bf16x8*)&As[cur][arow];
    const bf16x8 a1 = *(const bf16x8*)&As[cur][arow + 16 * 32];
#pragma unroll
    for (int nf = 0; nf < 8; ++nf) {
      const bf16x8 b = *(const bf16x8*)&Bs[cur][(nf * 16 + (l & 15)) * 32 + rslot];
      acc[0][nf] = __builtin_amdgcn_mfma_f32_16x16x32_bf16(a0, b, acc[0][nf], 0, 0, 0);
      acc[1][nf] = __builtin_amdgcn_mfma_f32_16x16x32_bf16(a1, b, acc[1][nf], 0, 0, 0);
    }
    __syncthreads();
  }
  const int rbase = m0 + w * 32 + (l >> 4) * 4;
  const int cbase = n0 + (l & 15);
#pragma unroll
  for (int m = 0; m < 2; ++m)
#pragma unroll
    for (int p = 0; p < 4; ++p) {
      const f32x4 up = acc[m][p];
      const f32x4 gt = acc[m][p + 4];
#pragma unroll
      for (int r = 0; r < 4; ++r) {
        const float u = up[r];
        const float s = (u / (1.f + expf(-u))) * gt[r];
        act[(size_t)(rbase + m * 16 + r) * IDIM + cbase + p * 16] = f2bf(s);
      }
    }
}

// grouped GEMM2: so[row][h] = act[row] @ W2T[e] (fp32 partials).
// BM=128, BN=128, 4 waves, wave tile 32x128 (acc[2][8]), 16 MFMA : 10 ds_read.
__launch_bounds__(256, 2)
__global__ void k_gemm2(const unsigned short* __restrict__ act,
                        const unsigned short* __restrict__ W2T,
                        const int* __restrict__ seg,
                        float* __restrict__ so) {
  __shared__ __align__(16) unsigned short As[2][128 * 32];
  __shared__ __align__(16) unsigned short Bs[2][128 * 32];
  const int tid = threadIdx.x;
  const int w = tid >> 6, l = tid & 63;
  const int m0 = blockIdx.y * 128;
  const int total = seg[NEXP];
  if (m0 >= total) return;
  int e = 0;
#pragma unroll
  for (int q = 1; q < NEXP; ++q) if (m0 >= seg[q]) e = q;
  const int n0 = blockIdx.x * 128;
  const int swz = ((tid & 3) ^ ((tid >> 3) & 3)) * 8;  // staging source col (elems)
  size_t aOff[2], bOff[2];
#pragma unroll
  for (int q = 0; q < 2; ++q) {
    aOff[q] = (size_t)(m0 + q * 64 + (tid >> 2)) * IDIM + swz;
    bOff[q] = ((size_t)e * HDIM + n0 + q * 64 + (tid >> 2)) * IDIM + swz;
  }

  f32x4 acc[2][8];
#pragma unroll
  for (int mf = 0; mf < 2; ++mf)
#pragma unroll
    for (int nf = 0; nf < 8; ++nf) acc[mf][nf] = (f32x4)0.f;

  auto stage = [&](int buf, int k0) {
#pragma unroll
    for (int q = 0; q < 2; ++q) {
      gld16(act + aOff[q] + k0, &As[buf][(q * 64 + (tid >> 2)) * 32 + (tid & 3) * 8]);
      gld16(W2T + bOff[q] + k0, &Bs[buf][(q * 64 + (tid >> 2)) * 32 + (tid & 3) * 8]);
    }
  };

  stage(0, 0);
  __syncthreads();
  const int rslot = ((l >> 4) ^ ((l >> 1) & 3)) * 8;   // swizzled read slot (elems)
  const int arow = (w * 32 + (l & 15)) * 32 + rslot;
  for (int t = 0; t < IDIM / 32; ++t) {
    const int cur = t & 1;
    if (t + 1 < IDIM / 32) stage(cur ^ 1, (t + 1) * 32);
    const bf16x8 a0 = *(const bf16x8*)&As[cur][arow];
    const bf16x8 a1 = *(const bf16x8*)&As[cur][arow + 16 * 32];
#pragma unroll
    for (int nf = 0; nf < 8; ++nf) {
      const bf16x8 b = *(const bf16x8*)&Bs[cur][(nf * 16 + (l & 15)) * 32 + rslot];
      acc[0][nf] = __builtin_amdgcn_mfma_f32_16x16x32_bf16(a0, b, acc[0][nf], 0, 0, 0);
      acc[1][nf] = __builtin_amdgcn_mfma_f32_16x16x32_bf16(a1, b, acc[1][nf], 0, 0, 0);
    }
    __syncthreads();
  }
  const int rbase = m0 + w * 32 + (l >> 4) * 4;
  const int cbase = n0 + (l & 15);
#pragma unroll
  for (int mf = 0; mf < 2; ++mf)
#pragma unroll
    for (int nf = 0; nf < 8; ++nf)
#pragma unroll
      for (int r = 0; r < 4; ++r)
        so[(size_t)(rbase + mf * 16 + r) * HDIM + cbase + nf * 16] = acc[mf][nf][r];
}

__global__ void k_combine(const float* __restrict__ so, const int* __restrict__ pos,
                          const float* __restrict__ rw, float* __restrict__ out) {
  const int t = blockIdx.x, i = threadIdx.x;
  const int p0 = pos[2 * t], p1 = pos[2 * t + 1];
  const float w0 = rw[2 * t], w1 = rw[2 * t + 1];
  const float4 a = ((const float4*)(so + (size_t)p0 * HDIM))[i];
  const float4 b = ((const float4*)(so + (size_t)p1 * HDIM))[i];
  float4 o;
  o.x = w0 * a.x + w1 * b.x;
  o.y = w0 * a.y + w1 * b.y;
  o.z = w0 * a.z + w1 * b.z;
  o.w = w0 * a.w + w1 * b.w;
  ((float4*)(out + (size_t)t * HDIM))[i] = o;
}

extern "C" void kernel_launch(void* const* d_in, const int* in_sizes, int n_in,
                              void* d_out, int out_size, void* d_ws, size_t ws_size,
                              hipStream_t stream) {
  const float* x  = (const float*)d_in[0];
  const float* Wg = (const float*)d_in[1];
  const float* W1 = (const float*)d_in[2];
  const float* W2 = (const float*)d_in[3];   // (E, I, H)
  const float* W3 = (const float*)d_in[4];   // (E, H, I)
  float* out = (float*)d_out;
  char* ws = (char*)d_ws;
  int*   idx  = (int*)(ws + OFF_IDX);
  float* rw   = (float*)(ws + OFF_RW);
  int*   seg  = (int*)(ws + OFF_SEG);
  int*   rowsv= (int*)(ws + OFF_ROWS);
  int*   pos  = (int*)(ws + OFF_POS);
  unsigned short* xb  = (unsigned short*)(ws + OFF_XB);
  unsigned short* W1T = (unsigned short*)(ws + OFF_W1T);
  unsigned short* W3T = (unsigned short*)(ws + OFF_W3T);
  unsigned short* W2T = (unsigned short*)(ws + OFF_W2T);
  unsigned short* act = (unsigned short*)(ws + OFF_ACT);
  float* so = (float*)(ws + OFF_SO);

  k_prep<<<dim3(32, 8, 26), 256, 0, stream>>>(W1, W3, W2, W1T, W3T, W2T,
                                              x, Wg, xb, idx, rw);
  k_segscatter<<<1, 256, 0, stream>>>(idx, seg, rowsv, pos);
  k_gemm1<<<dim3(IDIM / 64, NTM), 256, 0, stream>>>(xb, W1T, W3T, seg, rowsv, act);
  k_gemm2<<<dim3(HDIM / 128, NTM), 256, 0, stream>>>(act, W2T, seg, so);
  k_combine<<<NUM_TOK, 256, 0, stream>>>(so, pos, rw, out);
}

// Round 11
// 166.480 us; speedup vs baseline: 1.5225x; 1.1222x over previous
//
#include <hip/hip_runtime.h>
#include <math.h>

#define NUM_TOK 2048
#define HDIM 1024
#define IDIM 2048
#define NEXP 8
#define MAX_ROWS 5120
#define NTM 40

typedef __attribute__((ext_vector_type(8))) short bf16x8;
typedef __attribute__((ext_vector_type(4))) float f32x4;

// ---- workspace offsets (bytes) ----
#define OFF_IDX   0u
#define OFF_RW    16384u
#define OFF_SEG   32832u
#define OFF_ROWS  33024u
#define OFF_POS   53504u
#define OFF_XB    131072u
#define OFF_ACT   109051904u
#define OFF_SO    8388608u

__device__ __forceinline__ unsigned short f2bf(float f) {
  union { float f; unsigned u; } v; v.f = f;
  unsigned r = v.u + 0x7FFF + ((v.u >> 16) & 1);   // RNE
  return (unsigned short)(r >> 16);
}

__device__ __forceinline__ unsigned pk2(float lo, float hi) {
  return (unsigned)f2bf(lo) | ((unsigned)f2bf(hi) << 16);
}

__device__ __forceinline__ void gld16(const void* g, void* l) {
  __builtin_amdgcn_global_load_lds(
      (const __attribute__((address_space(1))) void*)g,
      (__attribute__((address_space(3))) void*)l, 16, 0, 0);
}

// Swizzle: logical 16B chunk c of LDS row r lives at phys chunk c ^ f(r&15),
// f(rg) = ((rg>>2)&3) ^ ((rg>>1)&3).  Applied at: A-stage source col,
// B-writer dword addr, fragment-read slot.  Fragment b128 reads: 2-way (free).
// B-writer b32 writes: 4-way (1.58x, bounded).

__global__ void k_router(const float* __restrict__ x, const float* __restrict__ wg,
                         unsigned short* __restrict__ xb,
                         int* __restrict__ idx, float* __restrict__ rw) {
  const int wave = threadIdx.x >> 6, lane = threadIdx.x & 63;
  const int t = blockIdx.x * 4 + wave;
  const float2* __restrict__ xr = (const float2*)(x + (size_t)t * HDIM);
  unsigned* __restrict__ xbr = (unsigned*)(xb + (size_t)t * HDIM);
  float acc[8];
#pragma unroll
  for (int q = 0; q < 8; ++q) acc[q] = 0.f;
#pragma unroll
  for (int j = 0; j < 8; ++j) {
    const int h2 = lane + (j << 6);
    const float2 v = xr[h2];
    const float* wrow = wg + (size_t)h2 * 16;
    const float4 a0 = *(const float4*)(wrow);
    const float4 a1 = *(const float4*)(wrow + 4);
    const float4 b0 = *(const float4*)(wrow + 8);
    const float4 b1 = *(const float4*)(wrow + 12);
    acc[0] = fmaf(v.x, a0.x, fmaf(v.y, b0.x, acc[0]));
    acc[1] = fmaf(v.x, a0.y, fmaf(v.y, b0.y, acc[1]));
    acc[2] = fmaf(v.x, a0.z, fmaf(v.y, b0.z, acc[2]));
    acc[3] = fmaf(v.x, a0.w, fmaf(v.y, b0.w, acc[3]));
    acc[4] = fmaf(v.x, a1.x, fmaf(v.y, b1.x, acc[4]));
    acc[5] = fmaf(v.x, a1.y, fmaf(v.y, b1.y, acc[5]));
    acc[6] = fmaf(v.x, a1.z, fmaf(v.y, b1.z, acc[6]));
    acc[7] = fmaf(v.x, a1.w, fmaf(v.y, b1.w, acc[7]));
    xbr[h2] = pk2(v.x, v.y);
  }
#pragma unroll
  for (int q = 0; q < 8; ++q) {
#pragma unroll
    for (int off = 32; off >= 1; off >>= 1)
      acc[q] += __shfl_xor(acc[q], off, 64);
  }
  if (lane == 0) {
    int i0 = 0; float v0 = acc[0];
#pragma unroll
    for (int q = 1; q < 8; ++q)
      if (acc[q] > v0) { v0 = acc[q]; i0 = q; }
    int i1 = -1; float v1 = -3.4e38f;
#pragma unroll
    for (int q = 0; q < 8; ++q)
      if (q != i0 && acc[q] > v1) { v1 = acc[q]; i1 = q; }
    const float e1 = expf(v1 - v0);
    const float inv = 1.f / (1.f + e1);
    idx[2 * t] = i0; idx[2 * t + 1] = i1;
    rw[2 * t] = inv; rw[2 * t + 1] = e1 * inv;
  }
}

// single block: histogram -> 128-aligned segments -> scatter
__global__ void k_segscatter(const int* __restrict__ idx, int* __restrict__ seg,
                             int* __restrict__ rowsv, int* __restrict__ pos) {
  __shared__ int hist[NEXP], cur[NEXP], sseg[NEXP];
  const int tid = threadIdx.x;
  if (tid < NEXP) { hist[tid] = 0; cur[tid] = 0; }
  __syncthreads();
  for (int s = tid; s < 2 * NUM_TOK; s += 256) atomicAdd(&hist[idx[s]], 1);
  for (int r = tid; r < MAX_ROWS; r += 256) rowsv[r] = -1;
  __syncthreads();
  if (tid == 0) {
    int s = 0;
    for (int q = 0; q < NEXP; ++q) {
      seg[q] = s; sseg[q] = s;
      s += ((hist[q] + 127) / 128) * 128;
    }
    seg[NEXP] = s;
  }
  __syncthreads();
  for (int s = tid; s < 2 * NUM_TOK; s += 256) {
    const int e = idx[s];
    const int p = atomicAdd(&cur[e], 1);
    const int rr = sseg[e] + p;
    rowsv[rr] = s;
    pos[s] = rr;
  }
}

// grouped GEMM1: act = silu(x@W1)*(x@W3).  B staged DIRECTLY from fp32 W1/W3:
// per K-step each thread reads 4 float4 (k-rows 2kk,2kk+1 of each matrix),
// packs k-pairs to bf16 dwords, ds_writes into swizzled Bs. T14 ordering:
// loads issued before MFMA block, writes after.
__launch_bounds__(256, 2)
__global__ void k_gemm1(const unsigned short* __restrict__ xb,
                        const float* __restrict__ W1f,
                        const float* __restrict__ W3f,
                        const int* __restrict__ seg, const int* __restrict__ rowsv,
                        unsigned short* __restrict__ act) {
  __shared__ __align__(16) unsigned short As[2][128 * 32];
  __shared__ __align__(16) unsigned short Bs[2][128 * 32];
  const int tid = threadIdx.x;
  const int w = tid >> 6, l = tid & 63;
  const int m0 = blockIdx.y * 128;
  const int total = seg[NEXP];
  if (m0 >= total) return;
  int e = 0;
#pragma unroll
  for (int q = 1; q < NEXP; ++q) if (m0 >= seg[q]) e = q;
  const int n0 = blockIdx.x * 64;

  // A staging (gld16): source col chunk = (l&3) ^ f(l>>2)
  const int swzA = ((l & 3) ^ ((l >> 4) & 3) ^ ((l >> 3) & 3)) * 8;
  size_t aOff[2];
#pragma unroll
  for (int q = 0; q < 2; ++q) {
    const int r = rowsv[m0 + w * 32 + q * 16 + (l >> 2)];
    const int tk = (r < 0) ? 0 : (r >> 1);
    aOff[q] = (size_t)tk * HDIM + swzA;
  }
  // B direct-from-fp32 staging
  const int kk = tid >> 4;            // 0..15 (k-pair index)
  const int ng = tid & 15;            // n-group (4 cols)
  const size_t bBase = (size_t)e * HDIM * IDIM + (size_t)(2 * kk) * IDIM + n0 + ng * 4;
  float4 u0, u1, g0, g1;
  auto loadB = [&](int k0) {
    const size_t b = bBase + (size_t)k0 * IDIM;
    u0 = *(const float4*)(W1f + b);
    u1 = *(const float4*)(W1f + b + IDIM);
    g0 = *(const float4*)(W3f + b);
    g1 = *(const float4*)(W3f + b + IDIM);
  };
  auto writeB = [&](int buf) {
    unsigned* Bd = (unsigned*)&Bs[buf][0];
    const float a0[4] = {u0.x, u0.y, u0.z, u0.w};
    const float a1[4] = {u1.x, u1.y, u1.z, u1.w};
    const float c0[4] = {g0.x, g0.y, g0.z, g0.w};
    const float c1[4] = {g1.x, g1.y, g1.z, g1.w};
#pragma unroll
    for (int i = 0; i < 4; ++i) {
      const int r = ng * 4 + i;                       // 0..63
      const int f = ((r >> 2) & 3) ^ ((r >> 1) & 3);
      const int d = (((kk >> 2) ^ f) << 2) + (kk & 3);
      Bd[r * 16 + d]        = pk2(a0[i], a1[i]);      // W1 rows 0..63
      Bd[(r + 64) * 16 + d] = pk2(c0[i], c1[i]);      // W3 rows 64..127
    }
  };
  auto stageA = [&](int buf, int k0) {
#pragma unroll
    for (int q = 0; q < 2; ++q)
      gld16(xb + aOff[q] + k0, &As[buf][(w * 32 + q * 16) * 32]);
  };

  f32x4 acc[2][8];
#pragma unroll
  for (int m = 0; m < 2; ++m)
#pragma unroll
    for (int nf = 0; nf < 8; ++nf) acc[m][nf] = (f32x4)0.f;

  stageA(0, 0);
  loadB(0);
  writeB(0);
  __syncthreads();

  const int rslot = ((l >> 4) ^ ((l >> 2) & 3) ^ ((l >> 1) & 3)) * 8;
  const int arow = (w * 32 + (l & 15)) * 32 + rslot;
  const int NT = HDIM / 32;
  for (int t = 0; t < NT; ++t) {
    const int cur = t & 1;
    if (t + 1 < NT) { stageA(cur ^ 1, (t + 1) * 32); loadB((t + 1) * 32); }
    __builtin_amdgcn_sched_barrier(0);
    const bf16x8 a0 = *(const bf16x8*)&As[cur][arow];
    const bf16x8 a1 = *(const bf16x8*)&As[cur][arow + 16 * 32];
#pragma unroll
    for (int nf = 0; nf < 8; ++nf) {
      const bf16x8 b = *(const bf16x8*)&Bs[cur][(nf * 16 + (l & 15)) * 32 + rslot];
      acc[0][nf] = __builtin_amdgcn_mfma_f32_16x16x32_bf16(a0, b, acc[0][nf], 0, 0, 0);
      acc[1][nf] = __builtin_amdgcn_mfma_f32_16x16x32_bf16(a1, b, acc[1][nf], 0, 0, 0);
    }
    if (t + 1 < NT) writeB(cur ^ 1);
    __syncthreads();
  }
  const int rbase = m0 + w * 32 + (l >> 4) * 4;
  const int cbase = n0 + (l & 15);
#pragma unroll
  for (int m = 0; m < 2; ++m)
#pragma unroll
    for (int p = 0; p < 4; ++p) {
      const f32x4 up = acc[m][p];
      const f32x4 gt = acc[m][p + 4];
#pragma unroll
      for (int r = 0; r < 4; ++r) {
        const float u = up[r];
        const float s = (u / (1.f + expf(-u))) * gt[r];
        act[(size_t)(rbase + m * 16 + r) * IDIM + cbase + p * 16] = f2bf(s);
      }
    }
}

// grouped GEMM2: so = act @ W2 (fp32 partials), B staged directly from fp32 W2.
// BM=128, BN=128, 4 waves, wave tile 32x128 (acc[2][8]).
__launch_bounds__(256, 2)
__global__ void k_gemm2(const unsigned short* __restrict__ act,
                        const float* __restrict__ W2f,
                        const int* __restrict__ seg,
                        float* __restrict__ so) {
  __shared__ __align__(16) unsigned short As[2][128 * 32];
  __shared__ __align__(16) unsigned short Bs[2][128 * 32];
  const int tid = threadIdx.x;
  const int w = tid >> 6, l = tid & 63;
  const int m0 = blockIdx.y * 128;
  const int total = seg[NEXP];
  if (m0 >= total) return;
  int e = 0;
#pragma unroll
  for (int q = 1; q < NEXP; ++q) if (m0 >= seg[q]) e = q;
  const int n0 = blockIdx.x * 128;

  const int swzA = ((tid & 3) ^ ((tid >> 4) & 3) ^ ((tid >> 3) & 3)) * 8;
  size_t aOff[2];
#pragma unroll
  for (int q = 0; q < 2; ++q)
    aOff[q] = (size_t)(m0 + q * 64 + (tid >> 2)) * IDIM + swzA;

  const int kk = tid >> 4;
  const int ng = tid & 15;
  const size_t bBase = (size_t)e * IDIM * HDIM + (size_t)(2 * kk) * HDIM + n0 + ng * 4;
  float4 v0[2], v1[2];
  auto loadB = [&](int k0) {
#pragma unroll
    for (int q = 0; q < 2; ++q) {
      const size_t b = bBase + (size_t)k0 * HDIM + q * 64;
      v0[q] = *(const float4*)(W2f + b);
      v1[q] = *(const float4*)(W2f + b + HDIM);
    }
  };
  auto writeB = [&](int buf) {
    unsigned* Bd = (unsigned*)&Bs[buf][0];
#pragma unroll
    for (int q = 0; q < 2; ++q) {
      const float a0[4] = {v0[q].x, v0[q].y, v0[q].z, v0[q].w};
      const float a1[4] = {v1[q].x, v1[q].y, v1[q].z, v1[q].w};
#pragma unroll
      for (int i = 0; i < 4; ++i) {
        const int rm = ng * 4 + i;                    // row mod 64
        const int f = ((rm >> 2) & 3) ^ ((rm >> 1) & 3);
        const int d = (((kk >> 2) ^ f) << 2) + (kk & 3);
        Bd[(q * 64 + rm) * 16 + d] = pk2(a0[i], a1[i]);
      }
    }
  };
  auto stageA = [&](int buf, int k0) {
#pragma unroll
    for (int q = 0; q < 2; ++q)
      gld16(act + aOff[q] + k0, &As[buf][(q * 64 + (tid >> 2)) * 32]);
  };

  f32x4 acc[2][8];
#pragma unroll
  for (int mf = 0; mf < 2; ++mf)
#pragma unroll
    for (int nf = 0; nf < 8; ++nf) acc[mf][nf] = (f32x4)0.f;

  stageA(0, 0);
  loadB(0);
  writeB(0);
  __syncthreads();

  const int rslot = ((l >> 4) ^ ((l >> 2) & 3) ^ ((l >> 1) & 3)) * 8;
  const int arow = (w * 32 + (l & 15)) * 32 + rslot;
  const int NT = IDIM / 32;
  for (int t = 0; t < NT; ++t) {
    const int cur = t & 1;
    if (t + 1 < NT) { stageA(cur ^ 1, (t + 1) * 32); loadB((t + 1) * 32); }
    __builtin_amdgcn_sched_barrier(0);
    const bf16x8 a0 = *(const bf16x8*)&As[cur][arow];
    const bf16x8 a1 = *(const bf16x8*)&As[cur][arow + 16 * 32];
#pragma unroll
    for (int nf = 0; nf < 8; ++nf) {
      const bf16x8 b = *(const bf16x8*)&Bs[cur][(nf * 16 + (l & 15)) * 32 + rslot];
      acc[0][nf] = __builtin_amdgcn_mfma_f32_16x16x32_bf16(a0, b, acc[0][nf], 0, 0, 0);
      acc[1][nf] = __builtin_amdgcn_mfma_f32_16x16x32_bf16(a1, b, acc[1][nf], 0, 0, 0);
    }
    if (t + 1 < NT) writeB(cur ^ 1);
    __syncthreads();
  }
  const int rbase = m0 + w * 32 + (l >> 4) * 4;
  const int cbase = n0 + (l & 15);
#pragma unroll
  for (int mf = 0; mf < 2; ++mf)
#pragma unroll
    for (int nf = 0; nf < 8; ++nf)
#pragma unroll
      for (int r = 0; r < 4; ++r)
        so[(size_t)(rbase + mf * 16 + r) * HDIM + cbase + nf * 16] = acc[mf][nf][r];
}

__global__ void k_combine(const float* __restrict__ so, const int* __restrict__ pos,
                          const float* __restrict__ rw, float* __restrict__ out) {
  const int t = blockIdx.x, i = threadIdx.x;
  const int p0 = pos[2 * t], p1 = pos[2 * t + 1];
  const float w0 = rw[2 * t], w1 = rw[2 * t + 1];
  const float4 a = ((const float4*)(so + (size_t)p0 * HDIM))[i];
  const float4 b = ((const float4*)(so + (size_t)p1 * HDIM))[i];
  float4 o;
  o.x = w0 * a.x + w1 * b.x;
  o.y = w0 * a.y + w1 * b.y;
  o.z = w0 * a.z + w1 * b.z;
  o.w = w0 * a.w + w1 * b.w;
  ((float4*)(out + (size_t)t * HDIM))[i] = o;
}

extern "C" void kernel_launch(void* const* d_in, const int* in_sizes, int n_in,
                              void* d_out, int out_size, void* d_ws, size_t ws_size,
                              hipStream_t stream) {
  const float* x  = (const float*)d_in[0];
  const float* Wg = (const float*)d_in[1];
  const float* W1 = (const float*)d_in[2];   // (E, H, I) fp32
  const float* W2 = (const float*)d_in[3];   // (E, I, H) fp32
  const float* W3 = (const float*)d_in[4];   // (E, H, I) fp32
  float* out = (float*)d_out;
  char* ws = (char*)d_ws;
  int*   idx  = (int*)(ws + OFF_IDX);
  float* rw   = (float*)(ws + OFF_RW);
  int*   seg  = (int*)(ws + OFF_SEG);
  int*   rowsv= (int*)(ws + OFF_ROWS);
  int*   pos  = (int*)(ws + OFF_POS);
  unsigned short* xb  = (unsigned short*)(ws + OFF_XB);
  unsigned short* act = (unsigned short*)(ws + OFF_ACT);
  float* so = (float*)(ws + OFF_SO);

  k_router<<<NUM_TOK / 4, 256, 0, stream>>>(x, Wg, xb, idx, rw);
  k_segscatter<<<1, 256, 0, stream>>>(idx, seg, rowsv, pos);
  k_gemm1<<<dim3(IDIM / 64, NTM), 256, 0, stream>>>(xb, W1, W3, seg, rowsv, act);
  k_gemm2<<<dim3(HDIM / 128, NTM), 256, 0, stream>>>(act, W2, seg, so);
  k_combine<<<NUM_TOK, 256, 0, stream>>>(so, pos, rw, out);
}

// Round 12
// 161.310 us; speedup vs baseline: 1.5713x; 1.0320x over previous
//
#include <hip/hip_runtime.h>
#include <math.h>

#define NUM_TOK 2048
#define HDIM 1024
#define IDIM 2048
#define NEXP 8
#define MAX_ROWS 5120
#define NTM 40

typedef __attribute__((ext_vector_type(8))) short bf16x8;
typedef __attribute__((ext_vector_type(4))) float f32x4;

// ---- workspace offsets (bytes) ----
#define OFF_IDX   0u
#define OFF_RW    16384u
#define OFF_SEG   32832u
#define OFF_ROWS  33024u
#define OFF_POS   53504u
#define OFF_XB    131072u
#define OFF_ACT   109051904u
#define OFF_SO    8388608u

// HW bf16 convert (v_cvt_pk_bf16_f32, RNE) via native __bf16 casts.
__device__ __forceinline__ unsigned short f2bf(float f) {
  __bf16 b = (__bf16)f;
  return __builtin_bit_cast(unsigned short, b);
}

__device__ __forceinline__ unsigned pk2(float lo, float hi) {
  __bf16 a = (__bf16)lo, b = (__bf16)hi;
  return (unsigned)__builtin_bit_cast(unsigned short, a) |
         ((unsigned)__builtin_bit_cast(unsigned short, b) << 16);
}

__device__ __forceinline__ void gld16(const void* g, void* l) {
  __builtin_amdgcn_global_load_lds(
      (const __attribute__((address_space(1))) void*)g,
      (__attribute__((address_space(3))) void*)l, 16, 0, 0);
}

// Swizzle: logical 16B chunk c of LDS row r lives at phys chunk c ^ f(r&15),
// f(rg) = ((rg>>2)&3) ^ ((rg>>1)&3).  Applied at: A-stage source col,
// B-writer dword addr, fragment-read slot.

__global__ void k_router(const float* __restrict__ x, const float* __restrict__ wg,
                         unsigned short* __restrict__ xb,
                         int* __restrict__ idx, float* __restrict__ rw) {
  const int wave = threadIdx.x >> 6, lane = threadIdx.x & 63;
  const int t = blockIdx.x * 4 + wave;
  const float2* __restrict__ xr = (const float2*)(x + (size_t)t * HDIM);
  unsigned* __restrict__ xbr = (unsigned*)(xb + (size_t)t * HDIM);
  float acc[8];
#pragma unroll
  for (int q = 0; q < 8; ++q) acc[q] = 0.f;
#pragma unroll
  for (int j = 0; j < 8; ++j) {
    const int h2 = lane + (j << 6);
    const float2 v = xr[h2];
    const float* wrow = wg + (size_t)h2 * 16;
    const float4 a0 = *(const float4*)(wrow);
    const float4 a1 = *(const float4*)(wrow + 4);
    const float4 b0 = *(const float4*)(wrow + 8);
    const float4 b1 = *(const float4*)(wrow + 12);
    acc[0] = fmaf(v.x, a0.x, fmaf(v.y, b0.x, acc[0]));
    acc[1] = fmaf(v.x, a0.y, fmaf(v.y, b0.y, acc[1]));
    acc[2] = fmaf(v.x, a0.z, fmaf(v.y, b0.z, acc[2]));
    acc[3] = fmaf(v.x, a0.w, fmaf(v.y, b0.w, acc[3]));
    acc[4] = fmaf(v.x, a1.x, fmaf(v.y, b1.x, acc[4]));
    acc[5] = fmaf(v.x, a1.y, fmaf(v.y, b1.y, acc[5]));
    acc[6] = fmaf(v.x, a1.z, fmaf(v.y, b1.z, acc[6]));
    acc[7] = fmaf(v.x, a1.w, fmaf(v.y, b1.w, acc[7]));
    xbr[h2] = pk2(v.x, v.y);
  }
#pragma unroll
  for (int q = 0; q < 8; ++q) {
#pragma unroll
    for (int off = 32; off >= 1; off >>= 1)
      acc[q] += __shfl_xor(acc[q], off, 64);
  }
  if (lane == 0) {
    int i0 = 0; float v0 = acc[0];
#pragma unroll
    for (int q = 1; q < 8; ++q)
      if (acc[q] > v0) { v0 = acc[q]; i0 = q; }
    int i1 = -1; float v1 = -3.4e38f;
#pragma unroll
    for (int q = 0; q < 8; ++q)
      if (q != i0 && acc[q] > v1) { v1 = acc[q]; i1 = q; }
    const float e1 = expf(v1 - v0);
    const float inv = 1.f / (1.f + e1);
    idx[2 * t] = i0; idx[2 * t + 1] = i1;
    rw[2 * t] = inv; rw[2 * t + 1] = e1 * inv;
  }
}

// single block: histogram -> 128-aligned segments -> scatter
__global__ void k_segscatter(const int* __restrict__ idx, int* __restrict__ seg,
                             int* __restrict__ rowsv, int* __restrict__ pos) {
  __shared__ int hist[NEXP], cur[NEXP], sseg[NEXP];
  const int tid = threadIdx.x;
  if (tid < NEXP) { hist[tid] = 0; cur[tid] = 0; }
  __syncthreads();
  for (int s = tid; s < 2 * NUM_TOK; s += 256) atomicAdd(&hist[idx[s]], 1);
  for (int r = tid; r < MAX_ROWS; r += 256) rowsv[r] = -1;
  __syncthreads();
  if (tid == 0) {
    int s = 0;
    for (int q = 0; q < NEXP; ++q) {
      seg[q] = s; sseg[q] = s;
      s += ((hist[q] + 127) / 128) * 128;
    }
    seg[NEXP] = s;
  }
  __syncthreads();
  for (int s = tid; s < 2 * NUM_TOK; s += 256) {
    const int e = idx[s];
    const int p = atomicAdd(&cur[e], 1);
    const int rr = sseg[e] + p;
    rowsv[rr] = s;
    pos[s] = rr;
  }
}

// grouped GEMM1: act = silu(x@W1)*(x@W3).  B staged DIRECTLY from fp32 W1/W3
// with 2-deep register prefetch (pA/pB sets) + HW cvt_pk packing.
__launch_bounds__(256, 2)
__global__ void k_gemm1(const unsigned short* __restrict__ xb,
                        const float* __restrict__ W1f,
                        const float* __restrict__ W3f,
                        const int* __restrict__ seg, const int* __restrict__ rowsv,
                        unsigned short* __restrict__ act) {
  __shared__ __align__(16) unsigned short As[2][128 * 32];
  __shared__ __align__(16) unsigned short Bs[2][128 * 32];
  const int tid = threadIdx.x;
  const int w = tid >> 6, l = tid & 63;
  const int m0 = blockIdx.y * 128;
  const int total = seg[NEXP];
  if (m0 >= total) return;
  int e = 0;
#pragma unroll
  for (int q = 1; q < NEXP; ++q) if (m0 >= seg[q]) e = q;
  const int n0 = blockIdx.x * 64;

  const int swzA = ((l & 3) ^ ((l >> 4) & 3) ^ ((l >> 3) & 3)) * 8;
  size_t aOff[2];
#pragma unroll
  for (int q = 0; q < 2; ++q) {
    const int r = rowsv[m0 + w * 32 + q * 16 + (l >> 2)];
    const int tk = (r < 0) ? 0 : (r >> 1);
    aOff[q] = (size_t)tk * HDIM + swzA;
  }
  const int kk = tid >> 4;            // 0..15 (k-pair index)
  const int ng = tid & 15;            // n-group (4 cols)
  const size_t bBase = (size_t)e * HDIM * IDIM + (size_t)(2 * kk) * IDIM + n0 + ng * 4;

  struct Bregs { float4 u0, u1, g0, g1; };
  auto loadB = [&](Bregs& p, int k0) {
    const size_t b = bBase + (size_t)k0 * IDIM;
    p.u0 = *(const float4*)(W1f + b);
    p.u1 = *(const float4*)(W1f + b + IDIM);
    p.g0 = *(const float4*)(W3f + b);
    p.g1 = *(const float4*)(W3f + b + IDIM);
  };
  auto writeB = [&](int buf, const Bregs& p) {
    unsigned* Bd = (unsigned*)&Bs[buf][0];
    const float a0[4] = {p.u0.x, p.u0.y, p.u0.z, p.u0.w};
    const float a1[4] = {p.u1.x, p.u1.y, p.u1.z, p.u1.w};
    const float c0[4] = {p.g0.x, p.g0.y, p.g0.z, p.g0.w};
    const float c1[4] = {p.g1.x, p.g1.y, p.g1.z, p.g1.w};
#pragma unroll
    for (int i = 0; i < 4; ++i) {
      const int r = ng * 4 + i;                       // 0..63
      const int f = ((r >> 2) & 3) ^ ((r >> 1) & 3);
      const int d = (((kk >> 2) ^ f) << 2) + (kk & 3);
      Bd[r * 16 + d]        = pk2(a0[i], a1[i]);      // W1 rows 0..63
      Bd[(r + 64) * 16 + d] = pk2(c0[i], c1[i]);      // W3 rows 64..127
    }
  };
  auto stageA = [&](int buf, int k0) {
#pragma unroll
    for (int q = 0; q < 2; ++q)
      gld16(xb + aOff[q] + k0, &As[buf][(w * 32 + q * 16) * 32]);
  };

  f32x4 acc[2][8];
#pragma unroll
  for (int m = 0; m < 2; ++m)
#pragma unroll
    for (int nf = 0; nf < 8; ++nf) acc[m][nf] = (f32x4)0.f;

  const int rslot = ((l >> 4) ^ ((l >> 2) & 3) ^ ((l >> 1) & 3)) * 8;
  const int arow = (w * 32 + (l & 15)) * 32 + rslot;
  auto mfmaStep = [&](int buf) {
    const bf16x8 a0 = *(const bf16x8*)&As[buf][arow];
    const bf16x8 a1 = *(const bf16x8*)&As[buf][arow + 16 * 32];
#pragma unroll
    for (int nf = 0; nf < 8; ++nf) {
      const bf16x8 b = *(const bf16x8*)&Bs[buf][(nf * 16 + (l & 15)) * 32 + rslot];
      acc[0][nf] = __builtin_amdgcn_mfma_f32_16x16x32_bf16(a0, b, acc[0][nf], 0, 0, 0);
      acc[1][nf] = __builtin_amdgcn_mfma_f32_16x16x32_bf16(a1, b, acc[1][nf], 0, 0, 0);
    }
  };

  Bregs pA, pB;
  loadB(pA, 0);
  stageA(0, 0);
  loadB(pB, 32);
  writeB(0, pA);
  __syncthreads();

  const int NT = HDIM / 32;   // 32, even
  for (int t = 0; t < NT; t += 2) {
    // leg A: compute buf0 = step t
    if (t + 2 < NT) loadB(pA, (t + 2) * 32);
    stageA(1, (t + 1) * 32);
    __builtin_amdgcn_sched_barrier(0);
    mfmaStep(0);
    writeB(1, pB);                    // step t+1
    __syncthreads();
    // leg B: compute buf1 = step t+1
    if (t + 3 < NT) loadB(pB, (t + 3) * 32);
    if (t + 2 < NT) stageA(0, (t + 2) * 32);
    __builtin_amdgcn_sched_barrier(0);
    mfmaStep(1);
    if (t + 2 < NT) writeB(0, pA);    // step t+2
    __syncthreads();
  }
  const int rbase = m0 + w * 32 + (l >> 4) * 4;
  const int cbase = n0 + (l & 15);
#pragma unroll
  for (int m = 0; m < 2; ++m)
#pragma unroll
    for (int p = 0; p < 4; ++p) {
      const f32x4 up = acc[m][p];
      const f32x4 gt = acc[m][p + 4];
#pragma unroll
      for (int r = 0; r < 4; ++r) {
        const float u = up[r];
        const float s = (u / (1.f + expf(-u))) * gt[r];
        act[(size_t)(rbase + m * 16 + r) * IDIM + cbase + p * 16] = f2bf(s);
      }
    }
}

// grouped GEMM2: so = act @ W2 (fp32 partials), B staged directly from fp32 W2
// with 2-deep register prefetch + HW cvt_pk.
__launch_bounds__(256, 2)
__global__ void k_gemm2(const unsigned short* __restrict__ act,
                        const float* __restrict__ W2f,
                        const int* __restrict__ seg,
                        float* __restrict__ so) {
  __shared__ __align__(16) unsigned short As[2][128 * 32];
  __shared__ __align__(16) unsigned short Bs[2][128 * 32];
  const int tid = threadIdx.x;
  const int w = tid >> 6, l = tid & 63;
  const int m0 = blockIdx.y * 128;
  const int total = seg[NEXP];
  if (m0 >= total) return;
  int e = 0;
#pragma unroll
  for (int q = 1; q < NEXP; ++q) if (m0 >= seg[q]) e = q;
  const int n0 = blockIdx.x * 128;

  const int swzA = ((tid & 3) ^ ((tid >> 4) & 3) ^ ((tid >> 3) & 3)) * 8;
  size_t aOff[2];
#pragma unroll
  for (int q = 0; q < 2; ++q)
    aOff[q] = (size_t)(m0 + q * 64 + (tid >> 2)) * IDIM + swzA;

  const int kk = tid >> 4;
  const int ng = tid & 15;
  const size_t bBase = (size_t)e * IDIM * HDIM + (size_t)(2 * kk) * HDIM + n0 + ng * 4;

  struct Bregs { float4 a0, a1, b0, b1; };   // two 64-col groups
  auto loadB = [&](Bregs& p, int k0) {
    const size_t b = bBase + (size_t)k0 * HDIM;
    p.a0 = *(const float4*)(W2f + b);
    p.a1 = *(const float4*)(W2f + b + HDIM);
    p.b0 = *(const float4*)(W2f + b + 64);
    p.b1 = *(const float4*)(W2f + b + HDIM + 64);
  };
  auto writeB = [&](int buf, const Bregs& p) {
    unsigned* Bd = (unsigned*)&Bs[buf][0];
    const float q00[4] = {p.a0.x, p.a0.y, p.a0.z, p.a0.w};
    const float q01[4] = {p.a1.x, p.a1.y, p.a1.z, p.a1.w};
    const float q10[4] = {p.b0.x, p.b0.y, p.b0.z, p.b0.w};
    const float q11[4] = {p.b1.x, p.b1.y, p.b1.z, p.b1.w};
#pragma unroll
    for (int i = 0; i < 4; ++i) {
      const int rm = ng * 4 + i;                    // row mod 64
      const int f = ((rm >> 2) & 3) ^ ((rm >> 1) & 3);
      const int d = (((kk >> 2) ^ f) << 2) + (kk & 3);
      Bd[rm * 16 + d]        = pk2(q00[i], q01[i]);
      Bd[(rm + 64) * 16 + d] = pk2(q10[i], q11[i]);
    }
  };
  auto stageA = [&](int buf, int k0) {
#pragma unroll
    for (int q = 0; q < 2; ++q)
      gld16(act + aOff[q] + k0, &As[buf][(q * 64 + (tid >> 2)) * 32]);
  };

  f32x4 acc[2][8];
#pragma unroll
  for (int mf = 0; mf < 2; ++mf)
#pragma unroll
    for (int nf = 0; nf < 8; ++nf) acc[mf][nf] = (f32x4)0.f;

  const int rslot = ((l >> 4) ^ ((l >> 2) & 3) ^ ((l >> 1) & 3)) * 8;
  const int arow = (w * 32 + (l & 15)) * 32 + rslot;
  auto mfmaStep = [&](int buf) {
    const bf16x8 a0 = *(const bf16x8*)&As[buf][arow];
    const bf16x8 a1 = *(const bf16x8*)&As[buf][arow + 16 * 32];
#pragma unroll
    for (int nf = 0; nf < 8; ++nf) {
      const bf16x8 b = *(const bf16x8*)&Bs[buf][(nf * 16 + (l & 15)) * 32 + rslot];
      acc[0][nf] = __builtin_amdgcn_mfma_f32_16x16x32_bf16(a0, b, acc[0][nf], 0, 0, 0);
      acc[1][nf] = __builtin_amdgcn_mfma_f32_16x16x32_bf16(a1, b, acc[1][nf], 0, 0, 0);
    }
  };

  Bregs pA, pB;
  loadB(pA, 0);
  stageA(0, 0);
  loadB(pB, 32);
  writeB(0, pA);
  __syncthreads();

  const int NT = IDIM / 32;   // 64, even
  for (int t = 0; t < NT; t += 2) {
    if (t + 2 < NT) loadB(pA, (t + 2) * 32);
    stageA(1, (t + 1) * 32);
    __builtin_amdgcn_sched_barrier(0);
    mfmaStep(0);
    writeB(1, pB);
    __syncthreads();
    if (t + 3 < NT) loadB(pB, (t + 3) * 32);
    if (t + 2 < NT) stageA(0, (t + 2) * 32);
    __builtin_amdgcn_sched_barrier(0);
    mfmaStep(1);
    if (t + 2 < NT) writeB(0, pA);
    __syncthreads();
  }
  const int rbase = m0 + w * 32 + (l >> 4) * 4;
  const int cbase = n0 + (l & 15);
#pragma unroll
  for (int mf = 0; mf < 2; ++mf)
#pragma unroll
    for (int nf = 0; nf < 8; ++nf)
#pragma unroll
      for (int r = 0; r < 4; ++r)
        so[(size_t)(rbase + mf * 16 + r) * HDIM + cbase + nf * 16] = acc[mf][nf][r];
}

__global__ void k_combine(const float* __restrict__ so, const int* __restrict__ pos,
                          const float* __restrict__ rw, float* __restrict__ out) {
  const int t = blockIdx.x, i = threadIdx.x;
  const int p0 = pos[2 * t], p1 = pos[2 * t + 1];
  const float w0 = rw[2 * t], w1 = rw[2 * t + 1];
  const float4 a = ((const float4*)(so + (size_t)p0 * HDIM))[i];
  const float4 b = ((const float4*)(so + (size_t)p1 * HDIM))[i];
  float4 o;
  o.x = w0 * a.x + w1 * b.x;
  o.y = w0 * a.y + w1 * b.y;
  o.z = w0 * a.z + w1 * b.z;
  o.w = w0 * a.w + w1 * b.w;
  ((float4*)(out + (size_t)t * HDIM))[i] = o;
}

extern "C" void kernel_launch(void* const* d_in, const int* in_sizes, int n_in,
                              void* d_out, int out_size, void* d_ws, size_t ws_size,
                              hipStream_t stream) {
  const float* x  = (const float*)d_in[0];
  const float* Wg = (const float*)d_in[1];
  const float* W1 = (const float*)d_in[2];   // (E, H, I) fp32
  const float* W2 = (const float*)d_in[3];   // (E, I, H) fp32
  const float* W3 = (const float*)d_in[4];   // (E, H, I) fp32
  float* out = (float*)d_out;
  char* ws = (char*)d_ws;
  int*   idx  = (int*)(ws + OFF_IDX);
  float* rw   = (float*)(ws + OFF_RW);
  int*   seg  = (int*)(ws + OFF_SEG);
  int*   rowsv= (int*)(ws + OFF_ROWS);
  int*   pos  = (int*)(ws + OFF_POS);
  unsigned short* xb  = (unsigned short*)(ws + OFF_XB);
  unsigned short* act = (unsigned short*)(ws + OFF_ACT);
  float* so = (float*)(ws + OFF_SO);

  k_router<<<NUM_TOK / 4, 256, 0, stream>>>(x, Wg, xb, idx, rw);
  k_segscatter<<<1, 256, 0, stream>>>(idx, seg, rowsv, pos);
  k_gemm1<<<dim3(IDIM / 64, NTM), 256, 0, stream>>>(xb, W1, W3, seg, rowsv, act);
  k_gemm2<<<dim3(HDIM / 128, NTM), 256, 0, stream>>>(act, W2, seg, so);
  k_combine<<<NUM_TOK, 256, 0, stream>>>(so, pos, rw, out);
}